// Round 5
// baseline (352.817 us; speedup 1.0000x reference)
//
#include <hip/hip_runtime.h>
#include <hip/hip_bf16.h>
#include <stdint.h>

typedef __bf16 bf16;
typedef __attribute__((ext_vector_type(8))) __bf16 bf16x8;
typedef __attribute__((ext_vector_type(4))) __bf16 bf16x4;
typedef __attribute__((ext_vector_type(4))) float  f32x4;

// ---- async global->LDS, 16B per lane, dest = wave-uniform base (+ lane*16 in HW) ----
static __device__ __forceinline__ void gll16(const void* g, void* lds_base) {
  __builtin_amdgcn_global_load_lds((__attribute__((address_space(1))) void*)g,
                                   (__attribute__((address_space(3))) void*)lds_base,
                                   16, 0, 0);
}

#define BARR  __builtin_amdgcn_s_barrier()
#define VMW(N) asm volatile("s_waitcnt vmcnt(" #N ")" ::: "memory")
#define LGKM0 do { asm volatile("s_waitcnt lgkmcnt(0)" ::: "memory");          \
                   __builtin_amdgcn_sched_barrier(0); } while (0)

// ============================================================================
// 256x256 BT-GEMM (D = A*B^T, K-contiguous, ld=1024), BK=64, 8 waves (2Mx4N),
// 4 phases per K-tile (snake quadrants Q00->Q01->Q11->Q10; both B-halves held
// in regs across the tile), double-buffered 128 KiB LDS, (row&7)<<4 XOR
// swizzle, counted vmcnt (never 0 in loop). Per-phase: {ds_read subtile ||
// stage one half-tile} -> BAR -> lgkm(0) -> 16 MFMA -> BAR.
//  gll path (VARIANT 2,3; bf16 A): P1 stage A1(u+1); P2 B0(u+2); P3 B1(u+2);
//    P4 A0(u+2), vmcnt(6).  [A-halves read at P1&P3 -> staged only at P4/P1]
//  fp32-A path (VARIANT 0,1): A via global_load->reg->cvt->swizzled ds_write:
//    P1 issue glbA0(u+2); P2 vm(8) wrA1(u+1), issue glbA1(u+2), gll B0(u+2);
//    P3 gll B1(u+2); P4 vm(8) wrA0(u+2).   (FIFO invariants verified)
// VARIANT: 0 proj->Cb row-major; 1 proj->v^T [b][h][t]; 2 qk->S (scale,
//   causal writes 0, pad -inf; jt==it+1 zero-fill, jt>it+1 skipped);
//   3 pv->Cf f32, K-loop causally truncated.
// ============================================================================
template <int VARIANT>
__global__ __launch_bounds__(512, 2) void gemm8(const void* __restrict__ Araw,
                                                const bf16* __restrict__ B,
                                                bf16* __restrict__ Cb,
                                                float* __restrict__ Cf,
                                                const int* __restrict__ pad) {
  constexpr bool FP32A = (VARIANT <= 1);
  extern __shared__ char smem[];         // A: 2 x 32KB | B: 2 x 32KB
  char* ldsA = smem;
  char* ldsB = smem + 65536;

  const int tid = threadIdx.x;
  const int lane = tid & 63, wave = tid >> 6;
  const int lo = lane & 15, hi = lane >> 4;
  const int wmi = wave >> 2, wni = wave & 3;
  const int swz = (lo & 7) << 4;         // read-side XOR key = (row&7)<<4

  const int nwg = gridDim.x;             // multiple of 8
  const int id = (blockIdx.x % 8) * (nwg >> 3) + blockIdx.x / 8;

  int row0, col0, nt, b = 0;
  if (VARIANT <= 1) {
    row0 = (id >> 2) * 256; col0 = (id & 3) * 256; nt = 16;
  } else {
    b = id >> 4;
    const int r = id & 15, it = r >> 2, jt = r & 3;
    row0 = it * 256; col0 = jt * 256;
    nt = (VARIANT == 3) ? min(16, 4 * it + 6) : 16;
    if (VARIANT == 2 && jt > it + 1) return;     // never read downstream
    if (VARIANT == 2 && jt == it + 1) {          // zero-fill (corner fixed later)
      bf16* Sb = Cb + ((size_t)b << 20);
      bf16x8 z = {};
#pragma unroll
      for (int q = 0; q < 16; ++q) {
        const int off = (q * 512 + tid) * 8;
        *(bf16x8*)(Sb + (size_t)(row0 + (off >> 8)) * 1024 + col0 + (off & 255)) = z;
      }
      return;
    }
  }
  const int ntm1 = nt - 1;
  const float* Afp = FP32A ? (const float*)Araw + (size_t)row0 * 1024 : nullptr;
  const bf16*  Ab  = FP32A ? nullptr
                           : (const bf16*)Araw + ((size_t)b << 20) + (size_t)row0 * 1024;
  const bf16*  Bp  = B + (FP32A ? (size_t)0 : ((size_t)b << 20)) + (size_t)col0 * 1024;

  f32x4 acc[8][4] = {};
  bf16x8 af[4][2], b0[2][2], b1[2][2];
  f32x4 rA0[4], rA1a[4], rA1b[4];

  // stage one 128-row half (16KB) of an operand K-tile: 2 gll/thread
  auto gllH = [&](const bf16* base, char* ldsOp, int h, int slot, int t) {
    const int tc = t > ntm1 ? ntm1 : t;
#pragma unroll
    for (int r = 0; r < 2; ++r) {
      const int x  = h * 16384 + (wave * 2 + r) * 1024 + lane * 16;
      const int xs = x ^ (((x >> 7) & 7) << 4);
      gll16((const char*)base + (size_t)(xs >> 7) * 2048 + (size_t)tc * 128 + (xs & 127),
            ldsOp + slot * 32768 + h * 16384 + (wave * 2 + r) * 1024);
    }
  };
  // fp32-A: load one half into regs (4x dwordx4/thread)
  auto glbA = [&](f32x4 rr[4], int h, int t) {
    const int tc = t > ntm1 ? ntm1 : t;
    const float* p = Afp + (size_t)(h * 128 + (tid >> 2)) * 1024 + (size_t)tc * 64 + (tid & 3) * 16;
#pragma unroll
    for (int j = 0; j < 4; ++j) rr[j] = *(const f32x4*)(p + j * 4);
  };
  // fp32-A: cvt + swizzled ds_write of one half (2x ds_write_b128/thread)
  auto wrA = [&](const f32x4 rr[4], int h, int slot) {
    const int rowh = tid >> 2, colb = (tid & 3) * 32, key = (rowh & 7) << 4;
    char* d = ldsA + slot * 32768 + h * 16384;
    bf16x8 o0 = { (bf16)rr[0][0], (bf16)rr[0][1], (bf16)rr[0][2], (bf16)rr[0][3],
                  (bf16)rr[1][0], (bf16)rr[1][1], (bf16)rr[1][2], (bf16)rr[1][3] };
    bf16x8 o1 = { (bf16)rr[2][0], (bf16)rr[2][1], (bf16)rr[2][2], (bf16)rr[2][3],
                  (bf16)rr[3][0], (bf16)rr[3][1], (bf16)rr[3][2], (bf16)rr[3][3] };
    *(bf16x8*)(d + ((rowh * 128 + colb) ^ key)) = o0;
    *(bf16x8*)(d + ((rowh * 128 + colb + 16) ^ key)) = o1;
  };
  auto rdA = [&](int mh, int slot) {
#pragma unroll
    for (int i = 0; i < 4; ++i)
#pragma unroll
      for (int kh = 0; kh < 2; ++kh) {
        const int row = wmi * 128 + mh * 64 + i * 16 + lo;
        af[i][kh] = *(const bf16x8*)(ldsA + slot * 32768 +
                                     ((row * 128 + kh * 64 + hi * 16) ^ swz));
      }
  };
  auto rdB = [&](bf16x8 dst[2][2], int nh, int slot) {
#pragma unroll
    for (int n = 0; n < 2; ++n)
#pragma unroll
      for (int kh = 0; kh < 2; ++kh) {
        const int row = wni * 64 + nh * 32 + n * 16 + lo;
        dst[n][kh] = *(const bf16x8*)(ldsB + slot * 32768 +
                                      ((row * 128 + kh * 64 + hi * 16) ^ swz));
      }
  };
  auto mmaQ = [&](bf16x8 bq[2][2], int mh, int nh) {
    __builtin_amdgcn_s_setprio(1);
#pragma unroll
    for (int i = 0; i < 4; ++i)
#pragma unroll
      for (int n = 0; n < 2; ++n)
#pragma unroll
        for (int kh = 0; kh < 2; ++kh)
          acc[mh * 4 + i][nh * 2 + n] = __builtin_amdgcn_mfma_f32_16x16x32_bf16(
              af[i][kh], bq[n][kh], acc[mh * 4 + i][nh * 2 + n], 0, 0, 0);
    __builtin_amdgcn_s_setprio(0);
  };

  // ---- prologue (FIFO invariants: see header comment) ----
  if constexpr (FP32A) {
    glbA(rA0, 0, 0);                       // A0(0)
    glbA(rA1a, 1, 0);                      // A1(0)
    glbA(rA1b, 0, 1);                      // A0(1) temp
    VMW(8);  wrA(rA0, 0, 0);
    VMW(4);  wrA(rA1a, 1, 0);
    VMW(0);  wrA(rA1b, 0, 1);
    gllH(Bp, ldsB, 0, 0, 0); gllH(Bp, ldsB, 1, 0, 0);
    glbA(rA1b, 1, 1);                      // A1(1)
    gllH(Bp, ldsB, 0, 1, 1); gllH(Bp, ldsB, 1, 1, 1);
    VMW(8);                                 // B(0) landed
    LGKM0; BARR;
  } else {
    gllH(Ab, ldsA, 0, 0, 0); gllH(Ab, ldsA, 1, 0, 0);
    gllH(Bp, ldsB, 0, 0, 0); gllH(Bp, ldsB, 1, 0, 0);
    gllH(Bp, ldsB, 0, 1, 1); gllH(Bp, ldsB, 1, 1, 1);
    gllH(Ab, ldsA, 0, 1, 1);
    VMW(6);                                 // tile0 landed; {B0,B1,A0}(1) in flight
    BARR;
  }

#define KTILE(U, CUR, RA1W, RA1L)                                              \
  /* P1 */                                                                     \
  rdA(0, CUR); rdB(b0, 0, CUR);                                                \
  if constexpr (FP32A) { glbA(rA0, 0, (U) + 2); }                              \
  else { gllH(Ab, ldsA, 1, (CUR) ^ 1, (U) + 1); }                              \
  BARR; LGKM0; mmaQ(b0, 0, 0); BARR;                                           \
  /* P2 */                                                                     \
  rdB(b1, 1, CUR);                                                             \
  if constexpr (FP32A) { VMW(8); wrA(RA1W, 1, (CUR) ^ 1); glbA(RA1L, 1, (U) + 2); } \
  gllH(Bp, ldsB, 0, CUR, (U) + 2);                                             \
  BARR; LGKM0; mmaQ(b1, 0, 1); BARR;                                           \
  /* P3 */                                                                     \
  rdA(1, CUR);                                                                 \
  gllH(Bp, ldsB, 1, CUR, (U) + 2);                                             \
  BARR; LGKM0; mmaQ(b1, 1, 1); BARR;                                           \
  /* P4 */                                                                     \
  if constexpr (FP32A) { VMW(8); wrA(rA0, 0, CUR); }                           \
  else { gllH(Ab, ldsA, 0, CUR, (U) + 2); }                                    \
  BARR; LGKM0; mmaQ(b0, 1, 0);                                                 \
  if constexpr (!FP32A) { VMW(6); }                                            \
  BARR;

  for (int u = 0; u < nt; u += 2) {        // nt is always even
    KTILE(u,     0, rA1b, rA1a)
    KTILE(u + 1, 1, rA1a, rA1b)
  }
#undef KTILE

  // ---- epilogue ----
  if (VARIANT == 0) {
#pragma unroll
    for (int m = 0; m < 8; ++m)
#pragma unroll
      for (int n = 0; n < 4; ++n) {
        const int c = col0 + wni * 64 + n * 16 + lo;
        const int rbase = row0 + wmi * 128 + m * 16 + hi * 4;
#pragma unroll
        for (int j = 0; j < 4; ++j)
          Cb[(size_t)(rbase + j) * 1024 + c] = (bf16)acc[m][n][j];
      }
  } else if (VARIANT == 1) {
#pragma unroll
    for (int m = 0; m < 8; ++m)
#pragma unroll
      for (int n = 0; n < 4; ++n) {
        const int r = row0 + wmi * 128 + m * 16 + hi * 4;
        const int c = col0 + wni * 64 + n * 16 + lo;
        const int bb = r >> 10, tt = r & 1023;
        bf16x4 h = { (bf16)acc[m][n][0], (bf16)acc[m][n][1],
                     (bf16)acc[m][n][2], (bf16)acc[m][n][3] };
        *(bf16x4*)(Cb + ((size_t)bb << 20) + ((size_t)c << 10) + tt) = h;
      }
  } else if (VARIANT == 2) {
    const float NINF = -__builtin_inff();
#pragma unroll
    for (int n = 0; n < 4; ++n) {
      const int s = col0 + wni * 64 + n * 16 + lo;
      const int pd = pad[(b << 10) + s];
#pragma unroll
      for (int m = 0; m < 8; ++m) {
        const int tbase = row0 + wmi * 128 + m * 16 + hi * 4;
#pragma unroll
        for (int j = 0; j < 4; ++j) {
          float v = acc[m][n][j] * 0.03125f;          // 1/sqrt(1024)
          if (s > tbase + j + 1) v = 0.f;             // causal: raw 0, softmax skips
          else if (pd != 0) v = NINF;                 // pad: true -inf inside width
          Cb[((size_t)b << 20) + (size_t)(tbase + j) * 1024 + s] = (bf16)v;
        }
      }
    }
  } else {
#pragma unroll
    for (int m = 0; m < 8; ++m)
#pragma unroll
      for (int n = 0; n < 4; ++n) {
        const int h2 = col0 + wni * 64 + n * 16 + lo;
        const int tbase = row0 + wmi * 128 + m * 16 + hi * 4;
#pragma unroll
        for (int j = 0; j < 4; ++j)
          Cf[((size_t)b << 20) + (size_t)(tbase + j) * 1024 + h2] = acc[m][n][j];
      }
  }
  asm volatile("s_waitcnt vmcnt(0)" ::: "memory");   // drain clamped stages before exit
}

// ---- fp32 -> bf16 elementwise (weights only) ----
__global__ __launch_bounds__(256) void cvt_kernel(const float* __restrict__ src,
                                                  bf16* __restrict__ dst, int n) {
  const int i = (blockIdx.x * 256 + threadIdx.x) * 8;
  if (i >= n) return;
  const f32x4 a = *(const f32x4*)(src + i);
  const f32x4 b = *(const f32x4*)(src + i + 4);
  bf16x8 o = { (bf16)a[0], (bf16)a[1], (bf16)a[2], (bf16)a[3],
               (bf16)b[0], (bf16)b[1], (bf16)b[2], (bf16)b[3] };
  *(bf16x8*)(dst + i) = o;
}

// ---- the single valid element on each jt==it+1 tile: S[t=it*256+255][s=(it+1)*256] ----
__global__ __launch_bounds__(64) void corner_kernel(const bf16* __restrict__ Q,
                                                    const bf16* __restrict__ K,
                                                    const int* __restrict__ pad,
                                                    bf16* __restrict__ S) {
  const int b = blockIdx.x / 3, it = blockIdx.x % 3;
  const int t = it * 256 + 255, s = (it + 1) * 256;
  const int lane = threadIdx.x;
  const bf16* q = Q + ((size_t)b << 20) + (size_t)t * 1024 + lane * 16;
  const bf16* k = K + ((size_t)b << 20) + (size_t)s * 1024 + lane * 16;
  bf16x8 q0 = *(const bf16x8*)q, q1 = *(const bf16x8*)(q + 8);
  bf16x8 k0 = *(const bf16x8*)k, k1 = *(const bf16x8*)(k + 8);
  float d = 0.f;
#pragma unroll
  for (int j = 0; j < 8; ++j) d += (float)q0[j] * (float)k0[j] + (float)q1[j] * (float)k1[j];
#pragma unroll
  for (int o = 32; o; o >>= 1) d += __shfl_xor(d, o, 64);
  if (lane == 0) {
    float v = d * 0.03125f;
    if (pad[(b << 10) + s] != 0) v = -__builtin_inff();
    S[((size_t)b << 20) + (size_t)t * 1024 + s] = (bf16)v;
  }
}

// ---- row softmax in place over valid prefix w = t+2 (causal tail stays 0) ----
__global__ __launch_bounds__(256) void softmax_kernel(bf16* __restrict__ S) {
  const int row  = blockIdx.x * 4 + (threadIdx.x >> 6);
  const int lane = threadIdx.x & 63;
  const int t = row & 1023;
  const int w = min(1024, t + 2);
  const bool act = lane * 16 < w;
  bf16* r = S + (size_t)row * 1024 + lane * 16;
  bf16x8 v0 = {}, v1 = {};
  float f[16];
#pragma unroll
  for (int j = 0; j < 16; ++j) f[j] = -1e30f;
  if (act) {
    v0 = *(const bf16x8*)r;
    v1 = *(const bf16x8*)(r + 8);
#pragma unroll
    for (int j = 0; j < 16; ++j)
      if (lane * 16 + j < w) f[j] = (float)(j < 8 ? v0[j] : v1[j - 8]);
  }
  float m = f[0];
#pragma unroll
  for (int j = 1; j < 16; ++j) m = fmaxf(m, f[j]);
#pragma unroll
  for (int o = 32; o; o >>= 1) m = fmaxf(m, __shfl_xor(m, o, 64));
  float sum = 0.f;
  float e[16];
#pragma unroll
  for (int j = 0; j < 16; ++j) { e[j] = __expf(f[j] - m); sum += e[j]; }
#pragma unroll
  for (int o = 32; o; o >>= 1) sum += __shfl_xor(sum, o, 64);
  const float inv = 1.0f / sum;
  if (act) {
#pragma unroll
    for (int j = 0; j < 8; ++j) {
      v0[j] = (bf16)(lane * 16 + j < w ? e[j] * inv : 0.f);
      v1[j] = (bf16)(lane * 16 + 8 + j < w ? e[8 + j] * inv : 0.f);
    }
    *(bf16x8*)r = v0;
    *(bf16x8*)(r + 8) = v1;
  }
}

extern "C" void kernel_launch(void* const* d_in, const int* in_sizes, int n_in,
                              void* d_out, int out_size, void* d_ws, size_t ws_size,
                              hipStream_t stream) {
  const float* key   = (const float*)d_in[0];
  const float* query = (const float*)d_in[1];
  const float* value = (const float*)d_in[2];
  const int*   pad   = (const int*)d_in[3];
  const float* Wk    = (const float*)d_in[4];
  const float* Wq    = (const float*)d_in[5];
  const float* Wv    = (const float*)d_in[6];
  float* out = (float*)d_out;

  // ws (bf16 elems): Wk,Wq,Wv (1M each) | q 16M | k 16M | vT 16M | S 16M
  bf16* Wkb = (bf16*)d_ws;
  bf16* Wqb = Wkb + (1 << 20);
  bf16* Wvb = Wqb + (1 << 20);
  bf16* qb  = Wvb + (1 << 20);
  bf16* kb  = qb  + (16 << 20);
  bf16* vT  = kb  + (16 << 20);
  bf16* S   = vT  + (16 << 20);

  hipFuncSetAttribute(reinterpret_cast<const void*>(&gemm8<0>),
                      hipFuncAttributeMaxDynamicSharedMemorySize, 131072);
  hipFuncSetAttribute(reinterpret_cast<const void*>(&gemm8<1>),
                      hipFuncAttributeMaxDynamicSharedMemorySize, 131072);
  hipFuncSetAttribute(reinterpret_cast<const void*>(&gemm8<2>),
                      hipFuncAttributeMaxDynamicSharedMemorySize, 131072);
  hipFuncSetAttribute(reinterpret_cast<const void*>(&gemm8<3>),
                      hipFuncAttributeMaxDynamicSharedMemorySize, 131072);

  cvt_kernel<<<512, 256, 0, stream>>>(Wk, Wkb, 1 << 20);
  cvt_kernel<<<512, 256, 0, stream>>>(Wq, Wqb, 1 << 20);
  cvt_kernel<<<512, 256, 0, stream>>>(Wv, Wvb, 1 << 20);

  gemm8<0><<<256, 512, 131072, stream>>>((const void*)query, Wqb, qb, nullptr, nullptr);
  gemm8<0><<<256, 512, 131072, stream>>>((const void*)key,   Wkb, kb, nullptr, nullptr);
  gemm8<1><<<256, 512, 131072, stream>>>((const void*)value, Wvb, vT, nullptr, nullptr);

  gemm8<2><<<256, 512, 131072, stream>>>((const void*)qb, kb, S, nullptr, pad);
  corner_kernel<<<48, 64, 0, stream>>>(qb, kb, pad, S);
  softmax_kernel<<<4096, 256, 0, stream>>>(S);
  gemm8<3><<<256, 512, 131072, stream>>>((const void*)S, vT, nullptr, out, nullptr);
}

// Round 6
// 248.536 us; speedup vs baseline: 1.4196x; 1.4196x over previous
//
#include <hip/hip_runtime.h>
#include <hip/hip_bf16.h>
#include <stdint.h>

typedef __bf16 bf16;
typedef __attribute__((ext_vector_type(8))) __bf16 bf16x8;
typedef __attribute__((ext_vector_type(4))) __bf16 bf16x4;
typedef __attribute__((ext_vector_type(4))) float  f32x4;

// ---- async global->LDS, 16B per lane, dest = wave-uniform base (+ lane*16 in HW) ----
static __device__ __forceinline__ void gll16(const void* g, void* lds_base) {
  __builtin_amdgcn_global_load_lds((__attribute__((address_space(1))) void*)g,
                                   (__attribute__((address_space(3))) void*)lds_base,
                                   16, 0, 0);
}

// ============================================================================
// 256x256 BT-GEMM (D = A*B^T, both K-contiguous, ld=1024), BK=64, 8 waves
// (2Mx4N), 2 phases per K-tile (B quarter held in regs across both phases),
// double-buffered 128 KiB LDS, (row&7)<<4 XOR-swizzle (0 bank conflicts,
// verified R4), counted vmcnt(4) once per K-tile. [R4-proven core: 42.5 us,
// 810 TF. R5's 4-phase + fp32-fused variants both regressed — reverted.]
// VARIANT: 0 proj -> Cb row-major [M][1024] bf16
//          1 proj -> Cb = per-batch transposed v^T [b][h][t] bf16
//          2 qk   -> Cb = S bf16 (scale; causal writes 0, pad -inf;
//                    jt==it+1 zero-fill, jt>it+1 skipped entirely)
//          3 pv   -> Cf = O f32, K-loop causally truncated
// ============================================================================
#define MFMA_CLUSTER(MQ)                                                       \
  __builtin_amdgcn_s_barrier();                                                \
  asm volatile("s_waitcnt lgkmcnt(0)" ::: "memory");                           \
  __builtin_amdgcn_sched_barrier(0);                                           \
  __builtin_amdgcn_s_setprio(1);                                               \
  _Pragma("unroll") for (int i_ = 0; i_ < 4; ++i_)                             \
  _Pragma("unroll") for (int n_ = 0; n_ < 4; ++n_)                             \
  _Pragma("unroll") for (int kh_ = 0; kh_ < 2; ++kh_)                          \
    acc[(MQ) * 4 + i_][n_] = __builtin_amdgcn_mfma_f32_16x16x32_bf16(          \
        af[i_][kh_], bfr[n_][kh_], acc[(MQ) * 4 + i_][n_], 0, 0, 0);           \
  __builtin_amdgcn_s_setprio(0);

template <int VARIANT>
__global__ __launch_bounds__(512, 2) void gemm8(const bf16* __restrict__ A,
                                                const bf16* __restrict__ B,
                                                bf16* __restrict__ Cb,
                                                float* __restrict__ Cf,
                                                const int* __restrict__ pad) {
  extern __shared__ char smem[];         // A: 2 x 32KB | B: 2 x 32KB
  char* ldsA = smem;
  char* ldsB = smem + 65536;

  const int tid = threadIdx.x;
  const int lane = tid & 63, wave = tid >> 6;
  const int lo = lane & 15, hi = lane >> 4;
  const int wmi = wave >> 2, wni = wave & 3;
  const int swz = (lo & 7) << 4;         // read-side XOR: (row&7)<<4, row&7 == lo&7

  // XCD-chunked bijective swizzle (gridDim.x % 8 == 0 for all launches)
  const int nwg = gridDim.x;
  const int id = (blockIdx.x % 8) * (nwg >> 3) + blockIdx.x / 8;

  int row0, col0, nt, b = 0;
  if (VARIANT <= 1) {
    row0 = (id >> 2) * 256; col0 = (id & 3) * 256; nt = 16;
  } else {
    b = id >> 4;
    const int r = id & 15, it = r >> 2, jt = r & 3;
    row0 = it * 256; col0 = jt * 256;
    nt = (VARIANT == 3) ? min(16, 4 * it + 6) : 16;
    if (VARIANT == 2 && jt > it + 1) return;     // never read downstream
    if (VARIANT == 2 && jt == it + 1) {          // zero-fill (corner fixed later)
      bf16* Sb = Cb + ((size_t)b << 20);
      bf16x8 z = {};
#pragma unroll
      for (int q = 0; q < 16; ++q) {
        const int off = (q * 512 + tid) * 8;
        *(bf16x8*)(Sb + (size_t)(row0 + (off >> 8)) * 1024 + col0 + (off & 255)) = z;
      }
      return;
    }
  }
  const bf16* Ap = A + ((size_t)b << 20) + (size_t)row0 * 1024;
  const bf16* Bp = B + ((size_t)b << 20) + (size_t)col0 * 1024;
  const int ntm1 = nt - 1;

  // stage one full 256x64 operand K-tile (32KB): 4 gll/wave, linear LDS dest,
  // inverse-swizzled global source (same involution as the read-side XOR).
  auto stgA = [&](int tidx, int slot) {
    const int tc = tidx > ntm1 ? ntm1 : tidx;   // clamped re-stage: slot never read again
#pragma unroll
    for (int r = 0; r < 4; ++r) {
      const int x  = (wave * 4 + r) * 1024 + lane * 16;
      const int xs = x ^ (((x >> 7) & 7) << 4);
      gll16((const char*)Ap + (size_t)(xs >> 7) * 2048 + (size_t)tc * 128 + (xs & 127),
            ldsA + slot * 32768 + (wave * 4 + r) * 1024);
    }
  };
  auto stgB = [&](int tidx, int slot) {
    const int tc = tidx > ntm1 ? ntm1 : tidx;
#pragma unroll
    for (int r = 0; r < 4; ++r) {
      const int x  = (wave * 4 + r) * 1024 + lane * 16;
      const int xs = x ^ (((x >> 7) & 7) << 4);
      gll16((const char*)Bp + (size_t)(xs >> 7) * 2048 + (size_t)tc * 128 + (xs & 127),
            ldsB + slot * 32768 + (wave * 4 + r) * 1024);
    }
  };

  f32x4 acc[8][4] = {};

  // prologue: establish steady-state invariant (tile0 landed, B(1) in flight)
  stgB(0, 0);
  stgA(0, 0);
  stgB(1, 1);
  asm volatile("s_waitcnt vmcnt(4)" ::: "memory");   // retire B(0),A(0); keep B(1)
  __builtin_amdgcn_s_barrier();

  bf16x8 af[4][2], bfr[4][2];
#pragma unroll 2
  for (int u = 0; u < nt; ++u) {
    const int cur = u & 1;
    // ---- Phase 1: A rows [wmi*128, +64) + ALL of wave's B quarter ----
#pragma unroll
    for (int i_ = 0; i_ < 4; ++i_)
#pragma unroll
      for (int kh_ = 0; kh_ < 2; ++kh_) {
        const int row_ = wmi * 128 + i_ * 16 + lo;
        af[i_][kh_] = *(const bf16x8*)(ldsA + cur * 32768 +
                                       ((row_ * 128 + kh_ * 64 + hi * 16) ^ swz));
      }
#pragma unroll
    for (int n_ = 0; n_ < 4; ++n_)
#pragma unroll
      for (int kh_ = 0; kh_ < 2; ++kh_) {
        const int row_ = wni * 64 + n_ * 16 + lo;
        bfr[n_][kh_] = *(const bf16x8*)(ldsB + cur * 32768 +
                                        ((row_ * 128 + kh_ * 64 + hi * 16) ^ swz));
      }
    stgA(u + 1, cur ^ 1);
    MFMA_CLUSTER(0)
    __builtin_amdgcn_s_barrier();
    // ---- Phase 2: A rows [wmi*128+64, +64), reuse bfr from registers ----
#pragma unroll
    for (int i_ = 0; i_ < 4; ++i_)
#pragma unroll
      for (int kh_ = 0; kh_ < 2; ++kh_) {
        const int row_ = wmi * 128 + 64 + i_ * 16 + lo;
        af[i_][kh_] = *(const bf16x8*)(ldsA + cur * 32768 +
                                       ((row_ * 128 + kh_ * 64 + hi * 16) ^ swz));
      }
    stgB(u + 2, cur);
    MFMA_CLUSTER(1)
    asm volatile("s_waitcnt vmcnt(4)" ::: "memory");  // retire A(u+1),B(u+1); keep B(u+2)
    __builtin_amdgcn_s_barrier();
  }

  // ---- epilogue ----
  if (VARIANT == 0) {
#pragma unroll
    for (int m = 0; m < 8; ++m)
#pragma unroll
      for (int n = 0; n < 4; ++n) {
        const int c = col0 + wni * 64 + n * 16 + lo;
        const int rbase = row0 + wmi * 128 + m * 16 + hi * 4;
#pragma unroll
        for (int j = 0; j < 4; ++j)
          Cb[(size_t)(rbase + j) * 1024 + c] = (bf16)acc[m][n][j];
      }
  } else if (VARIANT == 1) {
#pragma unroll
    for (int m = 0; m < 8; ++m)
#pragma unroll
      for (int n = 0; n < 4; ++n) {
        const int r = row0 + wmi * 128 + m * 16 + hi * 4;
        const int c = col0 + wni * 64 + n * 16 + lo;
        const int bb = r >> 10, tt = r & 1023;
        bf16x4 h = { (bf16)acc[m][n][0], (bf16)acc[m][n][1],
                     (bf16)acc[m][n][2], (bf16)acc[m][n][3] };
        *(bf16x4*)(Cb + ((size_t)bb << 20) + ((size_t)c << 10) + tt) = h;
      }
  } else if (VARIANT == 2) {
    const float NINF = -__builtin_inff();
#pragma unroll
    for (int n = 0; n < 4; ++n) {
      const int s = col0 + wni * 64 + n * 16 + lo;
      const int pd = pad[(b << 10) + s];
#pragma unroll
      for (int m = 0; m < 8; ++m) {
        const int tbase = row0 + wmi * 128 + m * 16 + hi * 4;
#pragma unroll
        for (int j = 0; j < 4; ++j) {
          float v = acc[m][n][j] * 0.03125f;          // 1/sqrt(1024)
          if (s > tbase + j + 1) v = 0.f;             // causal: raw 0, softmax skips
          else if (pd != 0) v = NINF;                 // pad: true -inf inside width
          Cb[((size_t)b << 20) + (size_t)(tbase + j) * 1024 + s] = (bf16)v;
        }
      }
    }
  } else {
#pragma unroll
    for (int m = 0; m < 8; ++m)
#pragma unroll
      for (int n = 0; n < 4; ++n) {
        const int h2 = col0 + wni * 64 + n * 16 + lo;
        const int tbase = row0 + wmi * 128 + m * 16 + hi * 4;
#pragma unroll
        for (int j = 0; j < 4; ++j)
          Cf[((size_t)b << 20) + (size_t)(tbase + j) * 1024 + h2] = acc[m][n][j];
      }
  }
  asm volatile("s_waitcnt vmcnt(0)" ::: "memory");   // drain clamped stages before exit
}

// ---- fp32 -> bf16 elementwise ----
__global__ __launch_bounds__(256) void cvt_kernel(const float* __restrict__ src,
                                                  bf16* __restrict__ dst, int n) {
  const int i = (blockIdx.x * 256 + threadIdx.x) * 8;
  if (i >= n) return;
  const f32x4 a = *(const f32x4*)(src + i);
  const f32x4 b = *(const f32x4*)(src + i + 4);
  bf16x8 o = { (bf16)a[0], (bf16)a[1], (bf16)a[2], (bf16)a[3],
               (bf16)b[0], (bf16)b[1], (bf16)b[2], (bf16)b[3] };
  *(bf16x8*)(dst + i) = o;
}

// ---- all three weight matrices in one launch (512 blocks each) ----
__global__ __launch_bounds__(256) void cvtW_kernel(const float* __restrict__ s0,
                                                   const float* __restrict__ s1,
                                                   const float* __restrict__ s2,
                                                   bf16* __restrict__ d0,
                                                   bf16* __restrict__ d1,
                                                   bf16* __restrict__ d2) {
  const int seg = blockIdx.x >> 9, blk = blockIdx.x & 511;
  const float* src = seg == 0 ? s0 : (seg == 1 ? s1 : s2);
  bf16* dst = seg == 0 ? d0 : (seg == 1 ? d1 : d2);
  const int i = (blk * 256 + threadIdx.x) * 8;
  const f32x4 a = *(const f32x4*)(src + i);
  const f32x4 b = *(const f32x4*)(src + i + 4);
  bf16x8 o = { (bf16)a[0], (bf16)a[1], (bf16)a[2], (bf16)a[3],
               (bf16)b[0], (bf16)b[1], (bf16)b[2], (bf16)b[3] };
  *(bf16x8*)(dst + i) = o;
}

// ---- the single valid element on each jt==it+1 tile: S[t=it*256+255][s=(it+1)*256] ----
__global__ __launch_bounds__(64) void corner_kernel(const bf16* __restrict__ Q,
                                                    const bf16* __restrict__ K,
                                                    const int* __restrict__ pad,
                                                    bf16* __restrict__ S) {
  const int b = blockIdx.x / 3, it = blockIdx.x % 3;
  const int t = it * 256 + 255, s = (it + 1) * 256;
  const int lane = threadIdx.x;
  const bf16* q = Q + ((size_t)b << 20) + (size_t)t * 1024 + lane * 16;
  const bf16* k = K + ((size_t)b << 20) + (size_t)s * 1024 + lane * 16;
  bf16x8 q0 = *(const bf16x8*)q, q1 = *(const bf16x8*)(q + 8);
  bf16x8 k0 = *(const bf16x8*)k, k1 = *(const bf16x8*)(k + 8);
  float d = 0.f;
#pragma unroll
  for (int j = 0; j < 8; ++j) d += (float)q0[j] * (float)k0[j] + (float)q1[j] * (float)k1[j];
#pragma unroll
  for (int o = 32; o; o >>= 1) d += __shfl_xor(d, o, 64);
  if (lane == 0) {
    float v = d * 0.03125f;
    if (pad[(b << 10) + s] != 0) v = -__builtin_inff();
    S[((size_t)b << 20) + (size_t)t * 1024 + s] = (bf16)v;
  }
}

// ---- row softmax in place over valid prefix w = t+2 (causal tail stays 0) ----
__global__ __launch_bounds__(256) void softmax_kernel(bf16* __restrict__ S) {
  const int row  = blockIdx.x * 4 + (threadIdx.x >> 6);
  const int lane = threadIdx.x & 63;
  const int t = row & 1023;
  const int w = min(1024, t + 2);
  const bool act = lane * 16 < w;
  bf16* r = S + (size_t)row * 1024 + lane * 16;
  bf16x8 v0 = {}, v1 = {};
  float f[16];
#pragma unroll
  for (int j = 0; j < 16; ++j) f[j] = -1e30f;
  if (act) {
    v0 = *(const bf16x8*)r;
    v1 = *(const bf16x8*)(r + 8);
#pragma unroll
    for (int j = 0; j < 16; ++j)
      if (lane * 16 + j < w) f[j] = (float)(j < 8 ? v0[j] : v1[j - 8]);
  }
  float m = f[0];
#pragma unroll
  for (int j = 1; j < 16; ++j) m = fmaxf(m, f[j]);
#pragma unroll
  for (int o = 32; o; o >>= 1) m = fmaxf(m, __shfl_xor(m, o, 64));
  float sum = 0.f;
  float e[16];
#pragma unroll
  for (int j = 0; j < 16; ++j) { e[j] = __expf(f[j] - m); sum += e[j]; }
#pragma unroll
  for (int o = 32; o; o >>= 1) sum += __shfl_xor(sum, o, 64);
  const float inv = 1.0f / sum;
  if (act) {
#pragma unroll
    for (int j = 0; j < 8; ++j) {
      v0[j] = (bf16)(lane * 16 + j < w ? e[j] * inv : 0.f);
      v1[j] = (bf16)(lane * 16 + 8 + j < w ? e[8 + j] * inv : 0.f);
    }
    *(bf16x8*)r = v0;
    *(bf16x8*)(r + 8) = v1;
  }
}

extern "C" void kernel_launch(void* const* d_in, const int* in_sizes, int n_in,
                              void* d_out, int out_size, void* d_ws, size_t ws_size,
                              hipStream_t stream) {
  const float* key   = (const float*)d_in[0];
  const float* query = (const float*)d_in[1];
  const float* value = (const float*)d_in[2];
  const int*   pad   = (const int*)d_in[3];
  const float* Wk    = (const float*)d_in[4];
  const float* Wq    = (const float*)d_in[5];
  const float* Wv    = (const float*)d_in[6];
  float* out = (float*)d_out;

  // ws (bf16 elems): Wk,Wq,Wv (1M each) | q 16M | k 16M | vT 16M | S 16M
  // S doubles as bf16-X scratch during projections (not live until qk).
  bf16* Wkb = (bf16*)d_ws;
  bf16* Wqb = Wkb + (1 << 20);
  bf16* Wvb = Wqb + (1 << 20);
  bf16* qb  = Wvb + (1 << 20);
  bf16* kb  = qb  + (16 << 20);
  bf16* vT  = kb  + (16 << 20);
  bf16* S   = vT  + (16 << 20);
  bf16* Xb  = S;

  hipFuncSetAttribute(reinterpret_cast<const void*>(&gemm8<0>),
                      hipFuncAttributeMaxDynamicSharedMemorySize, 131072);
  hipFuncSetAttribute(reinterpret_cast<const void*>(&gemm8<1>),
                      hipFuncAttributeMaxDynamicSharedMemorySize, 131072);
  hipFuncSetAttribute(reinterpret_cast<const void*>(&gemm8<2>),
                      hipFuncAttributeMaxDynamicSharedMemorySize, 131072);
  hipFuncSetAttribute(reinterpret_cast<const void*>(&gemm8<3>),
                      hipFuncAttributeMaxDynamicSharedMemorySize, 131072);

  cvtW_kernel<<<1536, 256, 0, stream>>>(Wk, Wq, Wv, Wkb, Wqb, Wvb);

  cvt_kernel<<<8192, 256, 0, stream>>>(query, Xb, 16 << 20);
  gemm8<0><<<256, 512, 131072, stream>>>(Xb, Wqb, qb, nullptr, nullptr);
  cvt_kernel<<<8192, 256, 0, stream>>>(key, Xb, 16 << 20);
  gemm8<0><<<256, 512, 131072, stream>>>(Xb, Wkb, kb, nullptr, nullptr);
  cvt_kernel<<<8192, 256, 0, stream>>>(value, Xb, 16 << 20);
  gemm8<1><<<256, 512, 131072, stream>>>(Xb, Wvb, vT, nullptr, nullptr);

  gemm8<2><<<256, 512, 131072, stream>>>(qb, kb, S, nullptr, pad);
  corner_kernel<<<48, 64, 0, stream>>>(qb, kb, pad, S);
  softmax_kernel<<<4096, 256, 0, stream>>>(S);
  gemm8<3><<<256, 512, 131072, stream>>>(S, vT, nullptr, out, nullptr);
}